// Round 8
// baseline (307.401 us; speedup 1.0000x reference)
//
#include <hip/hip_runtime.h>
#include <hip/hip_cooperative_groups.h>

#define NPTS 131072
#define NE 8
#define DIN 90
#define NH 256
#define NGMAX 2304  // max groups: 2048 full + <=255 bucket remainders

namespace cg = cooperative_groups;

typedef __attribute__((ext_vector_type(8))) short bf16x8;
typedef __attribute__((ext_vector_type(4))) float f32x4;
typedef __attribute__((ext_vector_type(2))) float f32x2;
typedef __attribute__((ext_vector_type(4))) unsigned int u32x4;
typedef __attribute__((ext_vector_type(2))) unsigned int u32x2;
typedef __attribute__((ext_vector_type(4), aligned(4))) float f32x4a;
typedef __attribute__((ext_vector_type(2), aligned(4))) float f32x2a;

// ---- ws layout (bytes) ----
#define WS_W1T   0         // 393216
#define WS_W2T   393216    // 65536
#define WS_PERM  458752    // 524288
#define WS_PHIST 983040    // 131072 (128 blocks x 256 buckets, no zeroing needed)
#define WS_BKTB  1114112   // 1024
#define WS_CUR   1115136   // 1024
#define WS_GTB   1116160   // 9216
#define WS_GTM   1125376   // 9216
#define WS_END   1134592

__device__ __forceinline__ unsigned short f2bf(float f) {
  unsigned int u = __float_as_uint(f);
  u += 0x7fffu + ((u >> 16) & 1u);
  return (unsigned short)(u >> 16);
}

#if defined(__has_builtin) && __has_builtin(__builtin_amdgcn_cvt_pk_bf16_f32)
typedef __attribute__((ext_vector_type(2))) __bf16 bf16x2;
__device__ __forceinline__ unsigned int pkbf(float f0, float f1) {
  bf16x2 r = __builtin_amdgcn_cvt_pk_bf16_f32(f0, f1);
  return __builtin_bit_cast(unsigned int, r);
}
#else
__device__ __forceinline__ unsigned int pkbf(float f0, float f1) {
  unsigned int u0 = __float_as_uint(f0) + 0x7fffu;
  unsigned int u1 = __float_as_uint(f1) + 0x7fffu;
  return __builtin_amdgcn_perm(u1, u0, 0x07060302u);
}
#endif

__device__ __forceinline__ bf16x8 cvt8(f32x4 a, f32x4 b) {
  u32x4 r;
  r[0] = pkbf(a[0], a[1]);
  r[1] = pkbf(a[2], a[3]);
  r[2] = pkbf(b[0], b[1]);
  r[3] = pkbf(b[2], b[3]);
  return __builtin_bit_cast(bf16x8, r);
}

// Survivor mask — arithmetic identical to the weight phase:
// expert survives iff !(dist > 2*min_dist). Zero-weight experts contribute
// EXACT 0 -> skipping is bit-identical (HW-verified R10/R12: absmax 0.0078125).
__device__ __forceinline__ int pmask(const float* __restrict__ gx,
                                     const float* __restrict__ cent) {
  float px = gx[0], py = gx[1], pz = gx[2];
  float d[NE];
  float mind = 3.4e38f;
#pragma unroll
  for (int e = 0; e < NE; ++e) {
    float dx = px - cent[e * 3 + 0];
    float dy = py - cent[e * 3 + 1];
    float dz = pz - cent[e * 3 + 2];
    float d2 = dx * dx + dy * dy + dz * dz;
    d[e] = sqrtf(fmaxf(d2, 0.f));
    mind = fminf(mind, d[e]);
  }
  int m = 0;
#pragma unroll
  for (int e = 0; e < NE; ++e)
    if (!(d[e] > 2.0f * mind)) m |= (1 << e);
  return m;
}

// ---- spill-proof inner-loop machinery (R12-proven: VGPR 84, no scratch) ----
#define UNRL _Pragma("unroll")

#define LOADW1(E_, C_, D0, D1, D2, D3, D4, D5)                                  \
  do {                                                                          \
    const unsigned short* _p =                                                  \
        W1T + (size_t)((E_) * NH + 128 * (C_) + 32 * wid + l15) * 96 + 8 * l4;  \
    D0 = *(const bf16x8*)(_p);                                                  \
    D1 = *(const bf16x8*)(_p + 32);                                             \
    D2 = *(const bf16x8*)(_p + 64);                                             \
    D3 = *(const bf16x8*)(_p + 1536);                                           \
    D4 = *(const bf16x8*)(_p + 1568);                                           \
    D5 = *(const bf16x8*)(_p + 1600);                                           \
  } while (0)

#define LOADBW(E_, C_, D)                                                       \
  do {                                                                          \
    D = *(const bf16x8*)(W2T + (size_t)((E_) * 16 + l15) * NH + 128 * (C_) +    \
                         32 * wid + 8 * l4);                                    \
  } while (0)

#define EPI(MF)                                                                 \
  UNRL for (int nf = 0; nf < 4; ++nf) {                                         \
    const float _w = wv[nf];                                                    \
    f32x4 _a = acc[nf];                                                         \
    f32x2 _p0, _p1;                                                             \
    _p0[0] = _a[0]; _p0[1] = _a[1];                                             \
    _p1[0] = _a[2]; _p1[1] = _a[3];                                             \
    const f32x2 _z = {0.f, 0.f};                                                \
    _p0 = __builtin_elementwise_max(_p0, _z) * _w;                              \
    _p1 = __builtin_elementwise_max(_p1, _z) * _w;                              \
    u32x2 _pk;                                                                  \
    _pk[0] = pkbf(_p0[0], _p0[1]);                                              \
    _pk[1] = pkbf(_p1[0], _p1[1]);                                              \
    *(u32x2*)&sH[gbase + (nf * 64 + (l15 + 16 * (2 * (MF) + (l4 >> 1)))) * 8 +  \
                 4 * (l4 & 1)] = _pk;                                           \
  }

#define STEP(E_, C_, LDWV_, EP_, CP_, CW0, CW1, CW2, CW3, CW4, CW5, CBW,        \
             NW0, NW1, NW2, NW3, NW4, NW5, NBW)                                 \
  do {                                                                          \
    const int _cb = 128 * (C_) + 32 * wid;                                      \
    f32x4 _b1v0 = *(const f32x4*)&sB1[(E_) * NH + _cb + 4 * l4];                \
    f32x4 _b1v1 = *(const f32x4*)&sB1[(E_) * NH + _cb + 16 + 4 * l4];           \
    if (LDWV_) {                                                                \
      UNRL for (int nf = 0; nf < 4; ++nf) wv[nf] = sW[(E_)][16 * nf + l15];     \
    }                                                                           \
    LOADBW(EP_, CP_, NBW);                                                      \
    LOADW1(EP_, CP_, NW0, NW1, NW2, NW3, NW4, NW5);                             \
    {                                                                           \
      f32x4 acc[4];                                                             \
      __builtin_amdgcn_s_setprio(1);                                            \
      UNRL for (int nf = 0; nf < 4; ++nf)                                       \
          acc[nf] = __builtin_amdgcn_mfma_f32_16x16x32_bf16(CW0, bfr[nf][0],    \
                                                            _b1v0, 0, 0, 0);    \
      UNRL for (int nf = 0; nf < 4; ++nf)                                       \
          acc[nf] = __builtin_amdgcn_mfma_f32_16x16x32_bf16(CW1, bfr[nf][1],    \
                                                            acc[nf], 0, 0, 0);  \
      UNRL for (int nf = 0; nf < 4; ++nf)                                       \
          acc[nf] = __builtin_amdgcn_mfma_f32_16x16x32_bf16(CW2, bfr[nf][2],    \
                                                            acc[nf], 0, 0, 0);  \
      __builtin_amdgcn_s_setprio(0);                                            \
      EPI(0)                                                                    \
      __builtin_amdgcn_s_setprio(1);                                            \
      UNRL for (int nf = 0; nf < 4; ++nf)                                       \
          acc[nf] = __builtin_amdgcn_mfma_f32_16x16x32_bf16(CW3, bfr[nf][0],    \
                                                            _b1v1, 0, 0, 0);    \
      UNRL for (int nf = 0; nf < 4; ++nf)                                       \
          acc[nf] = __builtin_amdgcn_mfma_f32_16x16x32_bf16(CW4, bfr[nf][1],    \
                                                            acc[nf], 0, 0, 0);  \
      UNRL for (int nf = 0; nf < 4; ++nf)                                       \
          acc[nf] = __builtin_amdgcn_mfma_f32_16x16x32_bf16(CW5, bfr[nf][2],    \
                                                            acc[nf], 0, 0, 0);  \
      __builtin_amdgcn_s_setprio(0);                                            \
      EPI(1)                                                                    \
    }                                                                           \
    __builtin_amdgcn_s_setprio(1);                                              \
    UNRL for (int rf = 0; rf < 4; ++rf) {                                       \
      bf16x8 _ah = *(const bf16x8*)&sH[gbase + (rf * 64 + lane) * 8];           \
      facc[rf] = __builtin_amdgcn_mfma_f32_16x16x32_bf16(_ah, CBW, facc[rf],    \
                                                         0, 0, 0);              \
    }                                                                           \
    __builtin_amdgcn_s_setprio(0);                                              \
  } while (0)

// ============================================================================
// R13: ONE cooperative kernel. R12 proved sparsity (main 75us) but its 5-launch
// chain cost ~98us of launch overhead (~20-25us/launch measured across R9/R12).
// R10 proved the coop skeleton is harness-safe + bit-exact; its 440us was the
// lambda-array scratch spill, fixed by R12's named-scalar STEP macros.
// Phases: A {W1/W2 prep || mask+partial-hist} | sync | B scan+tables (blk 0)
//         | sync | C scatter | sync | E grid-stride sparse main.
// Partial hists are written unconditionally -> no zero pass, no zero-ordering.
// ============================================================================
__global__ __launch_bounds__(256, 3) void mega2(
    const float* __restrict__ x, const float* __restrict__ cent,
    const float* __restrict__ b1, const float* __restrict__ b2,
    const float* __restrict__ W1, const float* __restrict__ W2,
    float* __restrict__ out,
    unsigned short* __restrict__ W1T, unsigned short* __restrict__ W2T,
    int* __restrict__ perm, int* __restrict__ phist, int* __restrict__ bktb,
    int* __restrict__ cursor, int* __restrict__ gt_base,
    int* __restrict__ gt_meta) {
  cg::grid_group gg = cg::this_grid();
  const int t   = threadIdx.x;
  const int blk = blockIdx.x;

  __shared__ unsigned short sH[4 * 2048];  // 16384 B; phases A-C scratch aliases here
  __shared__ float sW[NE][64];             // 2048 B
  __shared__ float sB2[64][4];             // 1024 B
  __shared__ float sB1[NE * NH];           // 8192 B
  __shared__ int sIdx[64];
  __shared__ int sElist[9];

  // ---------------- Phase A ----------------
  if (blk < 32) {
    // W1 [8][90][256] f32 -> W1T[(e*256+n)*96+kp] bf16, kp>=90 zero-padded
    const int e = blk >> 2;
    const int n0 = (blk & 3) * 64;
    unsigned int* ld = (unsigned int*)sH;  // [64][49] stride-49: conflict-free
    const int nl = t & 63;
    const int kq = t >> 6;
#pragma unroll
    for (int j = 0; j < 12; ++j) {
      const int kp2 = kq + 4 * j;
      const int k0 = 2 * kp2, k1 = k0 + 1;
      unsigned int lo = 0, hi = 0;
      if (k0 < DIN) lo = f2bf(W1[((size_t)e * DIN + k0) * NH + n0 + nl]);  // coalesced
      if (k1 < DIN) hi = f2bf(W1[((size_t)e * DIN + k1) * NH + n0 + nl]);
      ld[nl * 49 + kp2] = lo | (hi << 16);
    }
    __syncthreads();
    unsigned int* dst = (unsigned int*)(W1T + (size_t)(e * NH + n0) * 96);
#pragma unroll
    for (int j = 0; j < 12; ++j) {
      const int u = t + 256 * j;
      dst[u] = ld[(u / 48) * 49 + (u % 48)];  // coalesced stores
    }
  } else if (blk < 40) {
    // W2 [8][256][4] f32 -> W2T[(e*16+o)*NH + k] bf16, o>=4 zero-padded
    const int e = blk - 32;
    unsigned int* dst = (unsigned int*)W2T + (size_t)e * 2048;
    const float* src = W2 + (size_t)e * 1024;
#pragma unroll
    for (int j = 0; j < 8; ++j) {
      const int u = t + 256 * j;
      const int o = u >> 7, kp = u & 127;
      unsigned int v = 0;
      if (o < 4) {
        unsigned int lo = f2bf(src[(2 * kp) * 4 + o]);
        unsigned int hi = f2bf(src[(2 * kp + 1) * 4 + o]);
        v = lo | (hi << 16);
      }
      dst[u] = v;
    }
  } else if (blk < 168) {
    // mask partial histogram: 128 blocks x 1024 points, written unconditionally
    int* lh = (int*)sH;
    lh[t] = 0;
    __syncthreads();
    const int base = (blk - 40) * 1024;
#pragma unroll
    for (int j = 0; j < 4; ++j) {
      const int m = pmask(x + (size_t)(base + j * 256 + t) * 93, cent);
      atomicAdd(&lh[m], 1);
    }
    __syncthreads();
    phist[(blk - 40) * 256 + t] = lh[t];
  }
  gg.sync();

  // ---------------- Phase B: scan + group table + cursor zero (block 0) -----
  if (blk == 0) {
    int* s1 = (int*)sH;
    int* s2 = (int*)sH + 256;
    int c = 0;
    for (int b = 0; b < 128; ++b) c += phist[b * 256 + t];
    s1[t] = c;
    __syncthreads();
    for (int off = 1; off < 256; off <<= 1) {
      int a = s1[t];
      int bb = (t >= off) ? s1[t - off] : 0;
      __syncthreads();
      s1[t] = a + bb;
      __syncthreads();
    }
    const int base = s1[t] - c;
    bktb[t] = base;
    const int gc = (c + 63) >> 6;
    s2[t] = gc;
    __syncthreads();
    for (int off = 1; off < 256; off <<= 1) {
      int a = s2[t];
      int bb = (t >= off) ? s2[t - off] : 0;
      __syncthreads();
      s2[t] = a + bb;
      __syncthreads();
    }
    const int goff = s2[t] - gc;
    for (int j = 0; j < gc; ++j) {
      const int rem = c - 64 * j;
      gt_base[goff + j] = base + 64 * j;
      gt_meta[goff + j] = t | ((rem < 64 ? rem : 64) << 8);
    }
    cursor[t] = 0;
    __syncthreads();
    const int total = s2[255];
    for (int s = total + t; s < NGMAX; s += 256) gt_meta[s] = 0;
  }
  gg.sync();

  // ---------------- Phase C: scatter into mask buckets (blocks 0..127) ------
  if (blk < 128) {
    int* lh = (int*)sH;
    int* lb = (int*)sH + 256;
    int* lc = (int*)sH + 512;
    lh[t] = 0;
    lc[t] = 0;
    __syncthreads();
    const int base = blk * 1024;
    int m[4];
#pragma unroll
    for (int j = 0; j < 4; ++j) {
      m[j] = pmask(x + (size_t)(base + j * 256 + t) * 93, cent);  // L2-warm from A
      atomicAdd(&lh[m[j]], 1);
    }
    __syncthreads();
    if (lh[t] > 0) lb[t] = bktb[t] + atomicAdd(&cursor[t], lh[t]);
    __syncthreads();
#pragma unroll
    for (int j = 0; j < 4; ++j) {
      const int p = base + j * 256 + t;
      const int lp = atomicAdd(&lc[m[j]], 1);
      perm[lb[m[j]] + lp] = p;
    }
  }
  gg.sync();

  // ---------------- Phase E: sparse main, grid-stride over groups ----------
  const int lane = t & 63;
  const int wid  = t >> 6;
  const int l15  = lane & 15;
  const int l4   = lane >> 4;
  const int gbase = wid * 2048;

#pragma unroll
  for (int j = 0; j < 2; ++j)
    *(f32x4*)&sB1[t * 4 + j * 1024] = *(const f32x4a*)&b1[t * 4 + j * 1024];

  for (int g = blk; g < NGMAX; g += gridDim.x) {
    const int meta = gt_meta[g];
    const int cnt = meta >> 8;
    if (cnt == 0) continue;  // block-uniform
    const int gmask = meta & 255;
    const int base = gt_base[g];

    __syncthreads();  // covers sB1 (1st iter) + protects sIdx/sW/sB2/sH readers
    if (t < 64) sIdx[t] = perm[base + (t < cnt ? t : cnt - 1)];
    if (t == 0) {
      int ne = 0;
#pragma unroll
      for (int e = 0; e < NE; ++e)
        if ((gmask >> e) & 1) sElist[ne++] = e;
      sElist[8] = ne;
    }
    __syncthreads();

    // feat fragments (gathered rows)
    bf16x8 bfr[4][3];
#pragma unroll
    for (int nf = 0; nf < 4; ++nf) {
      const float* gr = x + (size_t)sIdx[16 * nf + l15] * 93 + 3;
      f32x4 v0, v1;
      v0 = *(const f32x4a*)(gr + 8 * l4);
      v1 = *(const f32x4a*)(gr + 8 * l4 + 4);
      bfr[nf][0] = cvt8(v0, v1);
      v0 = *(const f32x4a*)(gr + 32 + 8 * l4);
      v1 = *(const f32x4a*)(gr + 36 + 8 * l4);
      bfr[nf][1] = cvt8(v0, v1);
      if (l4 < 3) {
        v0 = *(const f32x4a*)(gr + 64 + 8 * l4);
        v1 = *(const f32x4a*)(gr + 68 + 8 * l4);
      } else {
        f32x2 tl = *(const f32x2a*)(gr + 88);
        v0[0] = tl[0]; v0[1] = tl[1]; v0[2] = 0.f; v0[3] = 0.f;
        v1[0] = 0.f; v1[1] = 0.f; v1[2] = 0.f; v1[3] = 0.f;
      }
      bfr[nf][2] = cvt8(v0, v1);
    }

    // per-point expert weights (arithmetic identical to pmask)
    if (t < 64) {
      const float* gx = x + (size_t)sIdx[t] * 93;
      float px = gx[0], py = gx[1], pz = gx[2];
      float dist[NE], inv[NE];
      float mind = 3.4e38f;
#pragma unroll
      for (int e = 0; e < NE; ++e) {
        float dx = px - cent[e * 3 + 0];
        float dy = py - cent[e * 3 + 1];
        float dz = pz - cent[e * 3 + 2];
        float d2 = dx * dx + dy * dy + dz * dz;
        float d = sqrtf(fmaxf(d2, 0.f));
        dist[e] = d;
        inv[e] = 1.f / (d + 1e-8f);
        mind = fminf(mind, d);
      }
      float s = 0.f;
#pragma unroll
      for (int e = 0; e < NE; ++e) {
        if (dist[e] > 2.0f * mind) inv[e] = 0.f;
        s += inv[e];
      }
      float rs = 1.f / s;
      float bb[4] = {0.f, 0.f, 0.f, 0.f};
#pragma unroll
      for (int e = 0; e < NE; ++e) {
        float w = inv[e] * rs;
        sW[e][t] = w;
#pragma unroll
        for (int o = 0; o < 4; ++o) bb[o] += w * b2[e * 4 + o];
      }
#pragma unroll
      for (int o = 0; o < 4; ++o) sB2[t][o] = bb[o];
    }
    __syncthreads();

    const int niter = 2 * sElist[8];

    bf16x8 w1A0, w1A1, w1A2, w1A3, w1A4, w1A5;
    bf16x8 w1B0, w1B1, w1B2, w1B3, w1B4, w1B5;
    bf16x8 bwA, bwB;
    float wv[4];
    f32x4 facc[4] = {{0.f, 0.f, 0.f, 0.f}, {0.f, 0.f, 0.f, 0.f},
                     {0.f, 0.f, 0.f, 0.f}, {0.f, 0.f, 0.f, 0.f}};

    {
      const int e0 = sElist[0];
      LOADBW(e0, 0, bwA);
      LOADW1(e0, 0, w1A0, w1A1, w1A2, w1A3, w1A4, w1A5);
    }

    for (int i = 0; i < niter; i += 2) {
      const int e = sElist[i >> 1];
      const int ip2 = (i + 2 < niter) ? (i + 2) : (i + 1);  // clamp: redundant reload
      const int e2 = sElist[ip2 >> 1];
      const int c2 = ip2 & 1;
      STEP(e, 0, 1, e, 1, w1A0, w1A1, w1A2, w1A3, w1A4, w1A5, bwA,
           w1B0, w1B1, w1B2, w1B3, w1B4, w1B5, bwB);
      STEP(e, 1, 0, e2, c2, w1B0, w1B1, w1B2, w1B3, w1B4, w1B5, bwB,
           w1A0, w1A1, w1A2, w1A3, w1A4, w1A5, bwA);
    }

    // cross-wave reduction (sOutP aliases sH)
    __syncthreads();
    float* sOutP = (float*)sH;
    if (l15 < 4) {
#pragma unroll
      for (int rf = 0; rf < 4; ++rf)
#pragma unroll
        for (int r = 0; r < 4; ++r)
          sOutP[(wid * 64 + 16 * rf + 4 * l4 + r) * 4 + l15] = facc[rf][r];
    }
    __syncthreads();
    {
      const int row = t >> 2, o = t & 3;
      if (row < cnt) {
        float v = sB2[row][o] + sOutP[(0 * 64 + row) * 4 + o] +
                  sOutP[(1 * 64 + row) * 4 + o] + sOutP[(2 * 64 + row) * 4 + o] +
                  sOutP[(3 * 64 + row) * 4 + o];
        out[(size_t)sIdx[row] * 4 + o] = v;
      }
    }
  }
}

// ============================================================================
// Fallback: proven dense 2-kernel path (163.6 us).
// ============================================================================
__global__ __launch_bounds__(256) void prep(const float* __restrict__ W1,
                                            const float* __restrict__ W2,
                                            unsigned short* __restrict__ W1T,
                                            unsigned short* __restrict__ W2T) {
  const int t = threadIdx.x;
  if (blockIdx.x < 32) {
    const int e = blockIdx.x >> 2;
    const int n0 = (blockIdx.x & 3) * 64;
    __shared__ unsigned int ld[64][49];
    const int nl = t & 63;
    const int kq = t >> 6;
#pragma unroll
    for (int j = 0; j < 12; ++j) {
      const int kp2 = kq + 4 * j;
      const int k0 = 2 * kp2, k1 = k0 + 1;
      unsigned int lo = 0, hi = 0;
      if (k0 < DIN) lo = f2bf(W1[((size_t)e * DIN + k0) * NH + n0 + nl]);
      if (k1 < DIN) hi = f2bf(W1[((size_t)e * DIN + k1) * NH + n0 + nl]);
      ld[nl][kp2] = lo | (hi << 16);
    }
    __syncthreads();
    unsigned int* dst = (unsigned int*)(W1T + (size_t)(e * NH + n0) * 96);
#pragma unroll
    for (int j = 0; j < 12; ++j) {
      const int u = t + 256 * j;
      dst[u] = ld[u / 48][u % 48];
    }
  } else {
    const int e = blockIdx.x - 32;
    unsigned int* dst = (unsigned int*)W2T + (size_t)e * 2048;
    const float* src = W2 + (size_t)e * 1024;
#pragma unroll
    for (int j = 0; j < 8; ++j) {
      const int u = t + 256 * j;
      const int o = u >> 7;
      const int kp = u & 127;
      unsigned int v = 0;
      if (o < 4) {
        unsigned int lo = f2bf(src[(2 * kp) * 4 + o]);
        unsigned int hi = f2bf(src[(2 * kp + 1) * 4 + o]);
        v = lo | (hi << 16);
      }
      dst[u] = v;
    }
  }
}

__global__ __launch_bounds__(256, 3) void meganerf_main(
    const float* __restrict__ x, const float* __restrict__ cent,
    const float* __restrict__ b1, const float* __restrict__ b2,
    const unsigned short* __restrict__ W1T, const unsigned short* __restrict__ W2T,
    float* __restrict__ out) {
  __shared__ unsigned short sH[4 * 2048];
  __shared__ float sW[NE][64];
  __shared__ float sB2[64][4];
  __shared__ float sB1[NE * NH];

  const int t    = threadIdx.x;
  const int lane = t & 63;
  const int wid  = t >> 6;
  const int l15  = lane & 15;
  const int l4   = lane >> 4;
  const int row0 = blockIdx.x * 64;
  const int gbase = wid * 2048;

#pragma unroll
  for (int j = 0; j < 2; ++j)
    *(f32x4*)&sB1[t * 4 + j * 1024] = *(const f32x4a*)&b1[t * 4 + j * 1024];

  bf16x8 bfr[4][3];
#pragma unroll
  for (int nf = 0; nf < 4; ++nf) {
    const float* gr = x + (size_t)(row0 + 16 * nf + l15) * 93 + 3;
    f32x4 v0, v1;
    v0 = *(const f32x4a*)(gr + 8 * l4);
    v1 = *(const f32x4a*)(gr + 8 * l4 + 4);
    bfr[nf][0] = cvt8(v0, v1);
    v0 = *(const f32x4a*)(gr + 32 + 8 * l4);
    v1 = *(const f32x4a*)(gr + 36 + 8 * l4);
    bfr[nf][1] = cvt8(v0, v1);
    if (l4 < 3) {
      v0 = *(const f32x4a*)(gr + 64 + 8 * l4);
      v1 = *(const f32x4a*)(gr + 68 + 8 * l4);
    } else {
      f32x2 tl = *(const f32x2a*)(gr + 88);
      v0[0] = tl[0]; v0[1] = tl[1]; v0[2] = 0.f; v0[3] = 0.f;
      v1[0] = 0.f; v1[1] = 0.f; v1[2] = 0.f; v1[3] = 0.f;
    }
    bfr[nf][2] = cvt8(v0, v1);
  }

  if (t < 64) {
    const float* gx = x + (size_t)(row0 + t) * 93;
    float px = gx[0], py = gx[1], pz = gx[2];
    float dist[NE], inv[NE];
    float mind = 3.4e38f;
#pragma unroll
    for (int e = 0; e < NE; ++e) {
      float dx = px - cent[e * 3 + 0];
      float dy = py - cent[e * 3 + 1];
      float dz = pz - cent[e * 3 + 2];
      float d2 = dx * dx + dy * dy + dz * dz;
      float d = sqrtf(fmaxf(d2, 0.f));
      dist[e] = d;
      inv[e] = 1.f / (d + 1e-8f);
      mind = fminf(mind, d);
    }
    float s = 0.f;
#pragma unroll
    for (int e = 0; e < NE; ++e) {
      if (dist[e] > 2.0f * mind) inv[e] = 0.f;
      s += inv[e];
    }
    float rs = 1.f / s;
    float bb[4] = {0.f, 0.f, 0.f, 0.f};
#pragma unroll
    for (int e = 0; e < NE; ++e) {
      float w = inv[e] * rs;
      sW[e][t] = w;
#pragma unroll
      for (int o = 0; o < 4; ++o) bb[o] += w * b2[e * 4 + o];
    }
#pragma unroll
    for (int o = 0; o < 4; ++o) sB2[t][o] = bb[o];
  }
  __syncthreads();

  bf16x8 w1A0, w1A1, w1A2, w1A3, w1A4, w1A5;
  bf16x8 w1B0, w1B1, w1B2, w1B3, w1B4, w1B5;
  bf16x8 bwA, bwB;
  float wv[4];
  f32x4 facc[4] = {{0.f, 0.f, 0.f, 0.f}, {0.f, 0.f, 0.f, 0.f},
                   {0.f, 0.f, 0.f, 0.f}, {0.f, 0.f, 0.f, 0.f}};

  LOADBW(0, 0, bwA);
  LOADW1(0, 0, w1A0, w1A1, w1A2, w1A3, w1A4, w1A5);

  for (int i = 0; i < 16; i += 2) {
    const int e = i >> 1;
    const int ip2 = (i + 2) & 15;
    const int e2 = ip2 >> 1;
    STEP(e, 0, 1, e, 1, w1A0, w1A1, w1A2, w1A3, w1A4, w1A5, bwA,
         w1B0, w1B1, w1B2, w1B3, w1B4, w1B5, bwB);
    STEP(e, 1, 0, e2, 0, w1B0, w1B1, w1B2, w1B3, w1B4, w1B5, bwB,
         w1A0, w1A1, w1A2, w1A3, w1A4, w1A5, bwA);
  }

  __syncthreads();
  float* sOutP = (float*)sH;
  if (l15 < 4) {
#pragma unroll
    for (int rf = 0; rf < 4; ++rf)
#pragma unroll
      for (int r = 0; r < 4; ++r)
        sOutP[(wid * 64 + 16 * rf + 4 * l4 + r) * 4 + l15] = facc[rf][r];
  }
  __syncthreads();
  {
    const int row = t >> 2, o = t & 3;
    float v = sB2[row][o] + sOutP[(0 * 64 + row) * 4 + o] + sOutP[(1 * 64 + row) * 4 + o] +
              sOutP[(2 * 64 + row) * 4 + o] + sOutP[(3 * 64 + row) * 4 + o];
    out[row0 * 4 + t] = v;
  }
}

extern "C" void kernel_launch(void* const* d_in, const int* in_sizes, int n_in,
                              void* d_out, int out_size, void* d_ws, size_t ws_size,
                              hipStream_t stream) {
  const float* x    = (const float*)d_in[0];
  const float* cent = (const float*)d_in[1];
  const float* W1   = (const float*)d_in[2];
  const float* b1   = (const float*)d_in[3];
  const float* W2   = (const float*)d_in[4];
  const float* b2   = (const float*)d_in[5];
  float* out = (float*)d_out;

  char* ws = (char*)d_ws;
  unsigned short* W1T = (unsigned short*)(ws + WS_W1T);
  unsigned short* W2T = (unsigned short*)(ws + WS_W2T);
  int* perm   = (int*)(ws + WS_PERM);
  int* phist  = (int*)(ws + WS_PHIST);
  int* bktb   = (int*)(ws + WS_BKTB);
  int* cursor = (int*)(ws + WS_CUR);
  int* gtb    = (int*)(ws + WS_GTB);
  int* gtm    = (int*)(ws + WS_GTM);

  static int nblk = -2;  // -2 unqueried, -1 unusable
  if (nblk == -2) {
    int bpc = 0;
    if (hipOccupancyMaxActiveBlocksPerMultiprocessor(&bpc, mega2, 256, 0) ==
            hipSuccess && bpc > 0) {
      long nb = (long)bpc * 256;  // 256 CUs
      nblk = nb > NGMAX ? NGMAX : (int)nb;
    } else {
      nblk = -1;
    }
  }

  bool ok = false;
  if (nblk >= 168 && ws_size >= (size_t)WS_END) {
    const float *xa = x, *ca = cent, *b1a = b1, *b2a = b2, *W1a = W1, *W2a = W2;
    float* oa = out;
    unsigned short *w1t = W1T, *w2t = W2T;
    int *pm = perm, *ph = phist, *bb = bktb, *cu = cursor, *g1 = gtb, *g2 = gtm;
    void* args[] = {&xa, &ca, &b1a, &b2a, &W1a, &W2a, &oa,
                    &w1t, &w2t, &pm, &ph, &bb, &cu, &g1, &g2};
    ok = hipLaunchCooperativeKernel(mega2, dim3(nblk), dim3(256), args, 0,
                                    stream) == hipSuccess;
  }
  if (!ok) {
    prep<<<40, 256, 0, stream>>>(W1, W2, W1T, W2T);
    meganerf_main<<<NPTS / 64, 256, 0, stream>>>(x, cent, b1, b2, W1T, W2T, out);
  }
}

// Round 10
// 171.913 us; speedup vs baseline: 1.7881x; 1.7881x over previous
//
#include <hip/hip_runtime.h>

#define NPTS 131072
#define NE 8
#define DIN 90
#define NH 256
#define NGMAX 2304  // max groups: 2048 full + <=255 bucket remainders

typedef __attribute__((ext_vector_type(8))) short bf16x8;
typedef __attribute__((ext_vector_type(4))) float f32x4;
typedef __attribute__((ext_vector_type(2))) float f32x2;
typedef __attribute__((ext_vector_type(4))) unsigned int u32x4;
typedef __attribute__((ext_vector_type(2))) unsigned int u32x2;
typedef __attribute__((ext_vector_type(4), aligned(4))) float f32x4a;
typedef __attribute__((ext_vector_type(2), aligned(4))) float f32x2a;

// ---- ws layout (bytes). END 1132544 <= R13's proven-available 1134592. ----
#define WS_W1T   0         // 393216
#define WS_W2T   393216    // 65536
#define WS_PERM  458752    // 524288
#define WS_PHIST 983040    // 131072 (128 blocks x 256 buckets, unconditional)
#define WS_GTB   1114112   // 9216
#define WS_GTM   1123328   // 9216
#define WS_END   1132544

__device__ __forceinline__ unsigned short f2bf(float f) {
  unsigned int u = __float_as_uint(f);
  u += 0x7fffu + ((u >> 16) & 1u);
  return (unsigned short)(u >> 16);
}

#if defined(__has_builtin) && __has_builtin(__builtin_amdgcn_cvt_pk_bf16_f32)
typedef __attribute__((ext_vector_type(2))) __bf16 bf16x2;
__device__ __forceinline__ unsigned int pkbf(float f0, float f1) {
  bf16x2 r = __builtin_amdgcn_cvt_pk_bf16_f32(f0, f1);
  return __builtin_bit_cast(unsigned int, r);
}
#else
__device__ __forceinline__ unsigned int pkbf(float f0, float f1) {
  unsigned int u0 = __float_as_uint(f0) + 0x7fffu;
  unsigned int u1 = __float_as_uint(f1) + 0x7fffu;
  return __builtin_amdgcn_perm(u1, u0, 0x07060302u);
}
#endif

__device__ __forceinline__ bf16x8 cvt8(f32x4 a, f32x4 b) {
  u32x4 r;
  r[0] = pkbf(a[0], a[1]);
  r[1] = pkbf(a[2], a[3]);
  r[2] = pkbf(b[0], b[1]);
  r[3] = pkbf(b[2], b[3]);
  return __builtin_bit_cast(bf16x8, r);
}

// Survivor mask — arithmetic identical to the weight phase. Zero-weight
// experts contribute EXACT 0 -> skipping is bit-identical (HW-verified
// R10/R12: absmax unchanged at 0.0078125).
__device__ __forceinline__ int pmask(const float* __restrict__ gx,
                                     const float* __restrict__ cent) {
  float px = gx[0], py = gx[1], pz = gx[2];
  float d[NE];
  float mind = 3.4e38f;
#pragma unroll
  for (int e = 0; e < NE; ++e) {
    float dx = px - cent[e * 3 + 0];
    float dy = py - cent[e * 3 + 1];
    float dz = pz - cent[e * 3 + 2];
    float d2 = dx * dx + dy * dy + dz * dz;
    d[e] = sqrtf(fmaxf(d2, 0.f));
    mind = fminf(mind, d[e]);
  }
  int m = 0;
#pragma unroll
  for (int e = 0; e < NE; ++e)
    if (!(d[e] > 2.0f * mind)) m |= (1 << e);
  return m;
}

// k1: blocks 0..127 mask partial hist (unconditional -> no zero pass),
//     128..159 W1 transpose, 160..167 W2 repack.
__global__ __launch_bounds__(256) void prep_mask2(
    const float* __restrict__ W1, const float* __restrict__ W2,
    const float* __restrict__ x, const float* __restrict__ cent,
    unsigned short* __restrict__ W1T, unsigned short* __restrict__ W2T,
    int* __restrict__ phist) {
  const int t = threadIdx.x;
  const int blk = blockIdx.x;
  __shared__ unsigned int shm[64 * 49];  // W1 tile / lhist (first 256 ints)
  if (blk < 128) {
    int* lh = (int*)shm;
    lh[t] = 0;
    __syncthreads();
    const int base = blk * 1024;
#pragma unroll
    for (int j = 0; j < 4; ++j) {
      const int m = pmask(x + (size_t)(base + j * 256 + t) * 93, cent);
      atomicAdd(&lh[m], 1);
    }
    __syncthreads();
    phist[blk * 256 + t] = lh[t];  // unconditional
  } else if (blk < 160) {
    // W1 [8][90][256] f32 -> W1T[(e*256+n)*96+kp] bf16, kp>=90 zero-padded
    const int e = (blk - 128) >> 2;
    const int n0 = ((blk - 128) & 3) * 64;
    const int nl = t & 63;
    const int kq = t >> 6;
#pragma unroll
    for (int j = 0; j < 12; ++j) {
      const int kp2 = kq + 4 * j;
      const int k0 = 2 * kp2, k1 = k0 + 1;
      unsigned int lo = 0, hi = 0;
      if (k0 < DIN) lo = f2bf(W1[((size_t)e * DIN + k0) * NH + n0 + nl]);  // coalesced
      if (k1 < DIN) hi = f2bf(W1[((size_t)e * DIN + k1) * NH + n0 + nl]);
      shm[nl * 49 + kp2] = lo | (hi << 16);  // stride 49: conflict-free
    }
    __syncthreads();
    unsigned int* dst = (unsigned int*)(W1T + (size_t)(e * NH + n0) * 96);
#pragma unroll
    for (int j = 0; j < 12; ++j) {
      const int u = t + 256 * j;
      dst[u] = shm[(u / 48) * 49 + (u % 48)];  // coalesced stores
    }
  } else {
    // W2 [8][256][4] f32 -> W2T[(e*16+o)*NH + k] bf16, o>=4 zero-padded
    const int e = blk - 160;
    unsigned int* dst = (unsigned int*)W2T + (size_t)e * 2048;
    const float* src = W2 + (size_t)e * 1024;
#pragma unroll
    for (int j = 0; j < 8; ++j) {
      const int u = t + 256 * j;
      const int o = u >> 7, kp = u & 127;
      unsigned int v = 0;
      if (o < 4) {
        unsigned int lo = f2bf(src[(2 * kp) * 4 + o]);
        unsigned int hi = f2bf(src[(2 * kp + 1) * 4 + o]);
        v = lo | (hi << 16);
      }
      dst[u] = v;
    }
  }
}

// k2: 128 blocks. Each block recomputes the bucket scan locally from phist
// (replaces scank launch) and derives its deterministic perm base from its
// phist prefix (replaces global cursor atomics + zerok). Block 0 also writes
// the group table.
__global__ __launch_bounds__(256) void scatter_tables(
    const float* __restrict__ x, const float* __restrict__ cent,
    const int* __restrict__ phist, int* __restrict__ perm,
    int* __restrict__ gt_base, int* __restrict__ gt_meta) {
  __shared__ int s1[256], s2[256], lbs[256], lc[256];
  const int t = threadIdx.x;
  const int b = blockIdx.x;

  int c = 0, pre = 0;
  for (int bb = 0; bb < 128; ++bb) {  // coalesced across t
    const int v = phist[bb * 256 + t];
    pre += (bb < b) ? v : 0;
    c += v;
  }
  s1[t] = c;
  __syncthreads();
  for (int off = 1; off < 256; off <<= 1) {
    int a = s1[t];
    int v = (t >= off) ? s1[t - off] : 0;
    __syncthreads();
    s1[t] = a + v;
    __syncthreads();
  }
  const int bkbase = s1[t] - c;  // exclusive bucket base
  lbs[t] = bkbase + pre;         // this block's segment start in bucket t
  lc[t] = 0;

  if (b == 0) {  // group table (block-uniform branch; barriers OK)
    const int gc = (c + 63) >> 6;
    s2[t] = gc;
    __syncthreads();
    for (int off = 1; off < 256; off <<= 1) {
      int a = s2[t];
      int v = (t >= off) ? s2[t - off] : 0;
      __syncthreads();
      s2[t] = a + v;
      __syncthreads();
    }
    const int goff = s2[t] - gc;
    for (int j = 0; j < gc; ++j) {
      const int rem = c - 64 * j;
      gt_base[goff + j] = bkbase + 64 * j;
      gt_meta[goff + j] = t | ((rem < 64 ? rem : 64) << 8);
    }
    __syncthreads();
    const int total = s2[255];
    for (int s = total + t; s < NGMAX; s += 256) gt_meta[s] = 0;
  }
  __syncthreads();  // lbs/lc ready

  const int pbase = b * 1024;
#pragma unroll
  for (int j = 0; j < 4; ++j) {
    const int p = pbase + j * 256 + t;
    const int m = pmask(x + (size_t)p * 93, cent);  // xyz L3-warm from k1
    const int lp = atomicAdd(&lc[m], 1);
    perm[lbs[m] + lp] = p;
  }
}

// ---- spill-proof inner-loop machinery (R12-proven: VGPR 84, no scratch) ----
#define UNRL _Pragma("unroll")

#define LOADW1(E_, C_, D0, D1, D2, D3, D4, D5)                                  \
  do {                                                                          \
    const unsigned short* _p =                                                  \
        W1T + (size_t)((E_) * NH + 128 * (C_) + 32 * wid + l15) * 96 + 8 * l4;  \
    D0 = *(const bf16x8*)(_p);                                                  \
    D1 = *(const bf16x8*)(_p + 32);                                             \
    D2 = *(const bf16x8*)(_p + 64);                                             \
    D3 = *(const bf16x8*)(_p + 1536);                                           \
    D4 = *(const bf16x8*)(_p + 1568);                                           \
    D5 = *(const bf16x8*)(_p + 1600);                                           \
  } while (0)

#define LOADBW(E_, C_, D)                                                       \
  do {                                                                          \
    D = *(const bf16x8*)(W2T + (size_t)((E_) * 16 + l15) * NH + 128 * (C_) +    \
                         32 * wid + 8 * l4);                                    \
  } while (0)

#define EPI(MF)                                                                 \
  UNRL for (int nf = 0; nf < 4; ++nf) {                                         \
    const float _w = wv[nf];                                                    \
    f32x4 _a = acc[nf];                                                         \
    f32x2 _p0, _p1;                                                             \
    _p0[0] = _a[0]; _p0[1] = _a[1];                                             \
    _p1[0] = _a[2]; _p1[1] = _a[3];                                             \
    const f32x2 _z = {0.f, 0.f};                                                \
    _p0 = __builtin_elementwise_max(_p0, _z) * _w;                              \
    _p1 = __builtin_elementwise_max(_p1, _z) * _w;                              \
    u32x2 _pk;                                                                  \
    _pk[0] = pkbf(_p0[0], _p0[1]);                                              \
    _pk[1] = pkbf(_p1[0], _p1[1]);                                              \
    *(u32x2*)&sH[gbase + (nf * 64 + (l15 + 16 * (2 * (MF) + (l4 >> 1)))) * 8 +  \
                 4 * (l4 & 1)] = _pk;                                           \
  }

#define STEP(E_, C_, LDWV_, EP_, CP_, CW0, CW1, CW2, CW3, CW4, CW5, CBW,        \
             NW0, NW1, NW2, NW3, NW4, NW5, NBW)                                 \
  do {                                                                          \
    const int _cb = 128 * (C_) + 32 * wid;                                      \
    f32x4 _b1v0 = *(const f32x4*)&sB1[(E_) * NH + _cb + 4 * l4];                \
    f32x4 _b1v1 = *(const f32x4*)&sB1[(E_) * NH + _cb + 16 + 4 * l4];           \
    if (LDWV_) {                                                                \
      UNRL for (int nf = 0; nf < 4; ++nf) wv[nf] = sW[(E_)][16 * nf + l15];     \
    }                                                                           \
    LOADBW(EP_, CP_, NBW);                                                      \
    LOADW1(EP_, CP_, NW0, NW1, NW2, NW3, NW4, NW5);                             \
    {                                                                           \
      f32x4 acc[4];                                                             \
      __builtin_amdgcn_s_setprio(1);                                            \
      UNRL for (int nf = 0; nf < 4; ++nf)                                       \
          acc[nf] = __builtin_amdgcn_mfma_f32_16x16x32_bf16(CW0, bfr[nf][0],    \
                                                            _b1v0, 0, 0, 0);    \
      UNRL for (int nf = 0; nf < 4; ++nf)                                       \
          acc[nf] = __builtin_amdgcn_mfma_f32_16x16x32_bf16(CW1, bfr[nf][1],    \
                                                            acc[nf], 0, 0, 0);  \
      UNRL for (int nf = 0; nf < 4; ++nf)                                       \
          acc[nf] = __builtin_amdgcn_mfma_f32_16x16x32_bf16(CW2, bfr[nf][2],    \
                                                            acc[nf], 0, 0, 0);  \
      __builtin_amdgcn_s_setprio(0);                                            \
      EPI(0)                                                                    \
      __builtin_amdgcn_s_setprio(1);                                            \
      UNRL for (int nf = 0; nf < 4; ++nf)                                       \
          acc[nf] = __builtin_amdgcn_mfma_f32_16x16x32_bf16(CW3, bfr[nf][0],    \
                                                            _b1v1, 0, 0, 0);    \
      UNRL for (int nf = 0; nf < 4; ++nf)                                       \
          acc[nf] = __builtin_amdgcn_mfma_f32_16x16x32_bf16(CW4, bfr[nf][1],    \
                                                            acc[nf], 0, 0, 0);  \
      UNRL for (int nf = 0; nf < 4; ++nf)                                       \
          acc[nf] = __builtin_amdgcn_mfma_f32_16x16x32_bf16(CW5, bfr[nf][2],    \
                                                            acc[nf], 0, 0, 0);  \
      __builtin_amdgcn_s_setprio(0);                                            \
      EPI(1)                                                                    \
    }                                                                           \
    __builtin_amdgcn_s_setprio(1);                                              \
    UNRL for (int rf = 0; rf < 4; ++rf) {                                       \
      bf16x8 _ah = *(const bf16x8*)&sH[gbase + (rf * 64 + lane) * 8];           \
      facc[rf] = __builtin_amdgcn_mfma_f32_16x16x32_bf16(_ah, CBW, facc[rf],    \
                                                         0, 0, 0);              \
    }                                                                           \
    __builtin_amdgcn_s_setprio(0);                                              \
  } while (0)

// k3: one mask-homogeneous 64-point group per block; 2*popcount(mask) steps.
// Prologue: direct perm reads (no sIdx LDS round-trip), weights spread over
// all 4 waves (lanes<16 each), ONE barrier instead of two.
__global__ __launch_bounds__(256, 3) void main_sparse(
    const float* __restrict__ x, const float* __restrict__ cent,
    const float* __restrict__ b1, const float* __restrict__ b2,
    const unsigned short* __restrict__ W1T, const unsigned short* __restrict__ W2T,
    const int* __restrict__ perm, const int* __restrict__ gt_base,
    const int* __restrict__ gt_meta, float* __restrict__ out) {
  const int meta = gt_meta[blockIdx.x];
  const int cnt = meta >> 8;
  if (cnt == 0) return;
  const int gmask = meta & 255;
  const int base = gt_base[blockIdx.x];

  __shared__ unsigned short sH[4 * 2048];  // 16384 B wave-private h
  __shared__ float sW[NE][64];             // 2048 B
  __shared__ float sB2[64][4];             // 1024 B
  __shared__ float sB1[NE * NH];           // 8192 B
  __shared__ int sElist[9];

  const int t    = threadIdx.x;
  const int lane = t & 63;
  const int wid  = t >> 6;
  const int l15  = lane & 15;
  const int l4   = lane >> 4;
  const int gbase = wid * 2048;

#pragma unroll
  for (int j = 0; j < 2; ++j)
    *(f32x4*)&sB1[t * 4 + j * 1024] = *(const f32x4a*)&b1[t * 4 + j * 1024];

  // ---- feat fragments: direct perm reads (16 distinct addrs -> 1-2 lines) ----
  bf16x8 bfr[4][3];
#pragma unroll
  for (int nf = 0; nf < 4; ++nf) {
    const int r = 16 * nf + l15;
    const int pidx = perm[base + (r < cnt ? r : cnt - 1)];
    const float* gr = x + (size_t)pidx * 93 + 3;
    f32x4 v0, v1;
    v0 = *(const f32x4a*)(gr + 8 * l4);
    v1 = *(const f32x4a*)(gr + 8 * l4 + 4);
    bfr[nf][0] = cvt8(v0, v1);
    v0 = *(const f32x4a*)(gr + 32 + 8 * l4);
    v1 = *(const f32x4a*)(gr + 36 + 8 * l4);
    bfr[nf][1] = cvt8(v0, v1);
    if (l4 < 3) {
      v0 = *(const f32x4a*)(gr + 64 + 8 * l4);
      v1 = *(const f32x4a*)(gr + 68 + 8 * l4);
    } else {
      f32x2 tl = *(const f32x2a*)(gr + 88);
      v0[0] = tl[0]; v0[1] = tl[1]; v0[2] = 0.f; v0[3] = 0.f;
      v1[0] = 0.f; v1[1] = 0.f; v1[2] = 0.f; v1[3] = 0.f;
    }
    bfr[nf][2] = cvt8(v0, v1);
  }

  // ---- weights: every wave handles its own 16 points (lanes 0..15) ----
  if (lane < 16) {
    const int pt = 16 * wid + lane;
    const int pidx = perm[base + (pt < cnt ? pt : cnt - 1)];
    const float* gx = x + (size_t)pidx * 93;
    float px = gx[0], py = gx[1], pz = gx[2];
    float dist[NE], inv[NE];
    float mind = 3.4e38f;
#pragma unroll
    for (int e = 0; e < NE; ++e) {
      float dx = px - cent[e * 3 + 0];
      float dy = py - cent[e * 3 + 1];
      float dz = pz - cent[e * 3 + 2];
      float d2 = dx * dx + dy * dy + dz * dz;
      float d = sqrtf(fmaxf(d2, 0.f));
      dist[e] = d;
      inv[e] = 1.f / (d + 1e-8f);
      mind = fminf(mind, d);
    }
    float s = 0.f;
#pragma unroll
    for (int e = 0; e < NE; ++e) {
      if (dist[e] > 2.0f * mind) inv[e] = 0.f;
      s += inv[e];
    }
    float rs = 1.f / s;
    float bb[4] = {0.f, 0.f, 0.f, 0.f};
#pragma unroll
    for (int e = 0; e < NE; ++e) {
      float w = inv[e] * rs;
      sW[e][pt] = w;
#pragma unroll
      for (int o = 0; o < 4; ++o) bb[o] += w * b2[e * 4 + o];
    }
#pragma unroll
    for (int o = 0; o < 4; ++o) sB2[pt][o] = bb[o];
  }
  if (t == 0) {
    int ne = 0;
#pragma unroll
    for (int e = 0; e < NE; ++e)
      if ((gmask >> e) & 1) sElist[ne++] = e;
    sElist[8] = ne;
  }
  __syncthreads();  // ONE barrier: sB1, sW, sB2, sElist all ready

  const int niter = 2 * sElist[8];

  bf16x8 w1A0, w1A1, w1A2, w1A3, w1A4, w1A5;
  bf16x8 w1B0, w1B1, w1B2, w1B3, w1B4, w1B5;
  bf16x8 bwA, bwB;
  float wv[4];
  f32x4 facc[4] = {{0.f, 0.f, 0.f, 0.f}, {0.f, 0.f, 0.f, 0.f},
                   {0.f, 0.f, 0.f, 0.f}, {0.f, 0.f, 0.f, 0.f}};

  {
    const int e0 = sElist[0];
    LOADBW(e0, 0, bwA);
    LOADW1(e0, 0, w1A0, w1A1, w1A2, w1A3, w1A4, w1A5);
  }

  for (int i = 0; i < niter; i += 2) {
    const int e = sElist[i >> 1];
    const int ip2 = (i + 2 < niter) ? (i + 2) : (i + 1);  // clamp: redundant reload
    const int e2 = sElist[ip2 >> 1];
    const int c2 = ip2 & 1;
    STEP(e, 0, 1, e, 1, w1A0, w1A1, w1A2, w1A3, w1A4, w1A5, bwA,
         w1B0, w1B1, w1B2, w1B3, w1B4, w1B5, bwB);
    STEP(e, 1, 0, e2, c2, w1B0, w1B1, w1B2, w1B3, w1B4, w1B5, bwB,
         w1A0, w1A1, w1A2, w1A3, w1A4, w1A5, bwA);
  }

  // ---- cross-wave reduction (sOutP aliases sH) ----
  __syncthreads();
  float* sOutP = (float*)sH;
  if (l15 < 4) {
#pragma unroll
    for (int rf = 0; rf < 4; ++rf)
#pragma unroll
      for (int r = 0; r < 4; ++r)
        sOutP[(wid * 64 + 16 * rf + 4 * l4 + r) * 4 + l15] = facc[rf][r];
  }
  __syncthreads();
  {
    const int row = t >> 2, o = t & 3;
    if (row < cnt) {
      const int pidx = perm[base + row];  // L1/L2-warm
      float v = sB2[row][o] + sOutP[(0 * 64 + row) * 4 + o] +
                sOutP[(1 * 64 + row) * 4 + o] + sOutP[(2 * 64 + row) * 4 + o] +
                sOutP[(3 * 64 + row) * 4 + o];
      out[(size_t)pidx * 4 + o] = v;
    }
  }
}

// ============================================================================
// Fallback: proven dense 2-kernel path.
// ============================================================================
__global__ __launch_bounds__(256) void prep(const float* __restrict__ W1,
                                            const float* __restrict__ W2,
                                            unsigned short* __restrict__ W1T,
                                            unsigned short* __restrict__ W2T) {
  const int t = threadIdx.x;
  if (blockIdx.x < 32) {
    const int e = blockIdx.x >> 2;
    const int n0 = (blockIdx.x & 3) * 64;
    __shared__ unsigned int ld[64][49];
    const int nl = t & 63;
    const int kq = t >> 6;
#pragma unroll
    for (int j = 0; j < 12; ++j) {
      const int kp2 = kq + 4 * j;
      const int k0 = 2 * kp2, k1 = k0 + 1;
      unsigned int lo = 0, hi = 0;
      if (k0 < DIN) lo = f2bf(W1[((size_t)e * DIN + k0) * NH + n0 + nl]);
      if (k1 < DIN) hi = f2bf(W1[((size_t)e * DIN + k1) * NH + n0 + nl]);
      ld[nl][kp2] = lo | (hi << 16);
    }
    __syncthreads();
    unsigned int* dst = (unsigned int*)(W1T + (size_t)(e * NH + n0) * 96);
#pragma unroll
    for (int j = 0; j < 12; ++j) {
      const int u = t + 256 * j;
      dst[u] = ld[u / 48][u % 48];
    }
  } else {
    const int e = blockIdx.x - 32;
    unsigned int* dst = (unsigned int*)W2T + (size_t)e * 2048;
    const float* src = W2 + (size_t)e * 1024;
#pragma unroll
    for (int j = 0; j < 8; ++j) {
      const int u = t + 256 * j;
      const int o = u >> 7;
      const int kp = u & 127;
      unsigned int v = 0;
      if (o < 4) {
        unsigned int lo = f2bf(src[(2 * kp) * 4 + o]);
        unsigned int hi = f2bf(src[(2 * kp + 1) * 4 + o]);
        v = lo | (hi << 16);
      }
      dst[u] = v;
    }
  }
}

__global__ __launch_bounds__(256, 3) void meganerf_main(
    const float* __restrict__ x, const float* __restrict__ cent,
    const float* __restrict__ b1, const float* __restrict__ b2,
    const unsigned short* __restrict__ W1T, const unsigned short* __restrict__ W2T,
    float* __restrict__ out) {
  __shared__ unsigned short sH[4 * 2048];
  __shared__ float sW[NE][64];
  __shared__ float sB2[64][4];
  __shared__ float sB1[NE * NH];

  const int t    = threadIdx.x;
  const int lane = t & 63;
  const int wid  = t >> 6;
  const int l15  = lane & 15;
  const int l4   = lane >> 4;
  const int row0 = blockIdx.x * 64;
  const int gbase = wid * 2048;

#pragma unroll
  for (int j = 0; j < 2; ++j)
    *(f32x4*)&sB1[t * 4 + j * 1024] = *(const f32x4a*)&b1[t * 4 + j * 1024];

  bf16x8 bfr[4][3];
#pragma unroll
  for (int nf = 0; nf < 4; ++nf) {
    const float* gr = x + (size_t)(row0 + 16 * nf + l15) * 93 + 3;
    f32x4 v0, v1;
    v0 = *(const f32x4a*)(gr + 8 * l4);
    v1 = *(const f32x4a*)(gr + 8 * l4 + 4);
    bfr[nf][0] = cvt8(v0, v1);
    v0 = *(const f32x4a*)(gr + 32 + 8 * l4);
    v1 = *(const f32x4a*)(gr + 36 + 8 * l4);
    bfr[nf][1] = cvt8(v0, v1);
    if (l4 < 3) {
      v0 = *(const f32x4a*)(gr + 64 + 8 * l4);
      v1 = *(const f32x4a*)(gr + 68 + 8 * l4);
    } else {
      f32x2 tl = *(const f32x2a*)(gr + 88);
      v0[0] = tl[0]; v0[1] = tl[1]; v0[2] = 0.f; v0[3] = 0.f;
      v1[0] = 0.f; v1[1] = 0.f; v1[2] = 0.f; v1[3] = 0.f;
    }
    bfr[nf][2] = cvt8(v0, v1);
  }

  if (t < 64) {
    const float* gx = x + (size_t)(row0 + t) * 93;
    float px = gx[0], py = gx[1], pz = gx[2];
    float dist[NE], inv[NE];
    float mind = 3.4e38f;
#pragma unroll
    for (int e = 0; e < NE; ++e) {
      float dx = px - cent[e * 3 + 0];
      float dy = py - cent[e * 3 + 1];
      float dz = pz - cent[e * 3 + 2];
      float d2 = dx * dx + dy * dy + dz * dz;
      float d = sqrtf(fmaxf(d2, 0.f));
      dist[e] = d;
      inv[e] = 1.f / (d + 1e-8f);
      mind = fminf(mind, d);
    }
    float s = 0.f;
#pragma unroll
    for (int e = 0; e < NE; ++e) {
      if (dist[e] > 2.0f * mind) inv[e] = 0.f;
      s += inv[e];
    }
    float rs = 1.f / s;
    float bb[4] = {0.f, 0.f, 0.f, 0.f};
#pragma unroll
    for (int e = 0; e < NE; ++e) {
      float w = inv[e] * rs;
      sW[e][t] = w;
#pragma unroll
      for (int o = 0; o < 4; ++o) bb[o] += w * b2[e * 4 + o];
    }
#pragma unroll
    for (int o = 0; o < 4; ++o) sB2[t][o] = bb[o];
  }
  __syncthreads();

  bf16x8 w1A0, w1A1, w1A2, w1A3, w1A4, w1A5;
  bf16x8 w1B0, w1B1, w1B2, w1B3, w1B4, w1B5;
  bf16x8 bwA, bwB;
  float wv[4];
  f32x4 facc[4] = {{0.f, 0.f, 0.f, 0.f}, {0.f, 0.f, 0.f, 0.f},
                   {0.f, 0.f, 0.f, 0.f}, {0.f, 0.f, 0.f, 0.f}};

  LOADBW(0, 0, bwA);
  LOADW1(0, 0, w1A0, w1A1, w1A2, w1A3, w1A4, w1A5);

  for (int i = 0; i < 16; i += 2) {
    const int e = i >> 1;
    const int ip2 = (i + 2) & 15;
    const int e2 = ip2 >> 1;
    STEP(e, 0, 1, e, 1, w1A0, w1A1, w1A2, w1A3, w1A4, w1A5, bwA,
         w1B0, w1B1, w1B2, w1B3, w1B4, w1B5, bwB);
    STEP(e, 1, 0, e2, 0, w1B0, w1B1, w1B2, w1B3, w1B4, w1B5, bwB,
         w1A0, w1A1, w1A2, w1A3, w1A4, w1A5, bwA);
  }

  __syncthreads();
  float* sOutP = (float*)sH;
  if (l15 < 4) {
#pragma unroll
    for (int rf = 0; rf < 4; ++rf)
#pragma unroll
      for (int r = 0; r < 4; ++r)
        sOutP[(wid * 64 + 16 * rf + 4 * l4 + r) * 4 + l15] = facc[rf][r];
  }
  __syncthreads();
  {
    const int row = t >> 2, o = t & 3;
    float v = sB2[row][o] + sOutP[(0 * 64 + row) * 4 + o] + sOutP[(1 * 64 + row) * 4 + o] +
              sOutP[(2 * 64 + row) * 4 + o] + sOutP[(3 * 64 + row) * 4 + o];
    out[row0 * 4 + t] = v;
  }
}

extern "C" void kernel_launch(void* const* d_in, const int* in_sizes, int n_in,
                              void* d_out, int out_size, void* d_ws, size_t ws_size,
                              hipStream_t stream) {
  const float* x    = (const float*)d_in[0];
  const float* cent = (const float*)d_in[1];
  const float* W1   = (const float*)d_in[2];
  const float* b1   = (const float*)d_in[3];
  const float* W2   = (const float*)d_in[4];
  const float* b2   = (const float*)d_in[5];
  float* out = (float*)d_out;

  char* ws = (char*)d_ws;
  unsigned short* W1T = (unsigned short*)(ws + WS_W1T);
  unsigned short* W2T = (unsigned short*)(ws + WS_W2T);
  int* perm  = (int*)(ws + WS_PERM);
  int* phist = (int*)(ws + WS_PHIST);
  int* gtb   = (int*)(ws + WS_GTB);
  int* gtm   = (int*)(ws + WS_GTM);

  if (ws_size >= (size_t)WS_END) {
    prep_mask2<<<168, 256, 0, stream>>>(W1, W2, x, cent, W1T, W2T, phist);
    scatter_tables<<<128, 256, 0, stream>>>(x, cent, phist, perm, gtb, gtm);
    main_sparse<<<NGMAX, 256, 0, stream>>>(x, cent, b1, b2, W1T, W2T, perm, gtb,
                                           gtm, out);
  } else {
    prep<<<40, 256, 0, stream>>>(W1, W2, W1T, W2T);
    meganerf_main<<<NPTS / 64, 256, 0, stream>>>(x, cent, b1, b2, W1T, W2T, out);
  }
}